// Round 9
// baseline (419.018 us; speedup 1.0000x reference)
//
#include <hip/hip_runtime.h>
#include <hip/hip_bf16.h>

typedef __bf16 bf16x8_t __attribute__((ext_vector_type(8)));
typedef float f32x4_t __attribute__((ext_vector_type(4)));

__device__ __forceinline__ float sigmoidf_(float x) { return 1.0f / (1.0f + __expf(-x)); }
__device__ __forceinline__ float siluf_(float x) { return x * sigmoidf_(x); }
__device__ __forceinline__ float softplusf_(float x) {
    return fmaxf(x, 0.0f) + log1pf(__expf(-fabsf(x)));
}
__device__ __forceinline__ float b2f(ushort u) { return __uint_as_float(((unsigned)u) << 16); }
__device__ __forceinline__ ushort f2b(float f) {
    return (ushort)__bfloat16_as_ushort(__float2bfloat16(f));
}
// Async global->LDS, 16 B/lane. LDS dest is wave-uniform base + lane*16;
// our tile layouts are contiguous in lane order (idx*16 bytes), so the
// per-lane computed pointer satisfies the m104 constraint.
__device__ __forceinline__ void gl_lds16(const void* g, void* l) {
    __builtin_amdgcn_global_load_lds(
        (const __attribute__((address_space(1))) unsigned int*)g,
        (__attribute__((address_space(3))) unsigned int*)l, 16, 0, 0);
}

// ---------------------------------------------------------------------------
// k_prep: (blocks 0..5311) cast+transpose weights fp32 [K][N] -> bf16 [N][K];
//         (blocks 5312..6335) transpose inputs (b,c,l) fp32 -> (b,l,c) bf16.
// ---------------------------------------------------------------------------
__global__ __launch_bounds__(256) void k_prep(
    const float* __restrict__ dec_w, const float* __restrict__ enc_w,
    const float* __restrict__ in_w, const float* __restrict__ m_out_w,
    const float* __restrict__ out_w, const float* __restrict__ x_proj_w,
    const float* __restrict__ dt_w,
    const float* __restrict__ dec, const float* __restrict__ enc,
    __hip_bfloat16* __restrict__ dec_wT, __hip_bfloat16* __restrict__ enc_wT,
    __hip_bfloat16* __restrict__ in_wT, __hip_bfloat16* __restrict__ m_out_wT,
    __hip_bfloat16* __restrict__ out_wT, __hip_bfloat16* __restrict__ xpwT,
    __hip_bfloat16* __restrict__ dtwT,
    __hip_bfloat16* __restrict__ decL, __hip_bfloat16* __restrict__ encL)
{
    __shared__ float tile[64][65];
    if (blockIdx.x < 5312) {
        int gid = blockIdx.x * 256 + threadIdx.x;
        const float* src; __hip_bfloat16* dst; int lk, N, idx;
        if (gid < 262144)       { src = dec_w;    dst = dec_wT;   lk = 8; N = 1024; idx = gid; }
        else if (gid < 393216)  { src = enc_w;    dst = enc_wT;   lk = 8; N = 512;  idx = gid - 262144; }
        else if (gid < 917504)  { src = in_w;     dst = in_wT;    lk = 9; N = 1024; idx = gid - 393216; }
        else if (gid < 1179648) { src = m_out_w;  dst = m_out_wT; lk = 9; N = 512;  idx = gid - 917504; }
        else if (gid < 1310720) { src = out_w;    dst = out_wT;   lk = 9; N = 256;  idx = gid - 1179648; }
        else if (gid < 1343488) { src = x_proj_w; dst = xpwT;     lk = 9; N = 64;   idx = gid - 1310720; }
        else                    { src = dt_w;     dst = dtwT;     lk = 5; N = 512;  idx = gid - 1343488; }
        int K = 1 << lk;
        int n = idx >> lk, k = idx & (K - 1);
        dst[idx] = __float2bfloat16(src[(size_t)k * N + n]);
        return;
    }
    const int bid = blockIdx.x - 5312;
    const int t = threadIdx.x;
    const int ct = bid & 3;
    const int lt = (bid >> 2) & 63;
    const int sel = bid >> 8;
    const int b = sel & 1, ten = sel >> 1;
    const float* src = ten ? enc : dec;
    __hip_bfloat16* dst = ten ? encL : decL;
    const size_t ibase = (size_t)b * 256 * 4096 + (size_t)(ct * 64) * 4096 + (size_t)lt * 64;
#pragma unroll
    for (int i = 0; i < 16; ++i) {
        int c = i * 4 + (t >> 6), l = t & 63;
        tile[c][l] = src[ibase + (size_t)c * 4096 + l];
    }
    __syncthreads();
    const size_t obase = ((size_t)b * 4096 + (size_t)lt * 64) * 256 + ct * 64;
#pragma unroll
    for (int i = 0; i < 16; ++i) {
        int l = i * 4 + (t >> 6), c = t & 63;
        dst[obase + (size_t)l * 256 + c] = __float2bfloat16(tile[c][l]);
    }
}

// ---------------------------------------------------------------------------
// bf16 MFMA GEMM (128x128 tile, BK=32, 4 waves of 64x64).
// Staging via async global_load_lds (16 B/lane) -- no VGPR round-trip.
// EPI 0: enc_p bf16 | EPI 1: combined bf16 + sigmoid(gate) bf16 (extra=enc_p)
// EPI 2: xm/silu(z) bf16 | EPI 3: v * extra (gate_sig bf16)
// ---------------------------------------------------------------------------
template <int EPI, int K>
__global__ __launch_bounds__(256) void bgemm(
    const __hip_bfloat16* __restrict__ A, const __hip_bfloat16* __restrict__ Bt,
    const float* __restrict__ bias, void* __restrict__ out0,
    void* __restrict__ out1, const void* __restrict__ extra)
{
    __shared__ ushort At[128 * 32];
    __shared__ ushort Bl[128 * 32];
    const int tid = threadIdx.x;
    const int wave = tid >> 6, lane = tid & 63;
    const int n0 = blockIdx.x * 128, m0 = blockIdx.y * 128;
    const int wm = (wave >> 1) * 64, wn = (wave & 1) * 64;
    f32x4_t acc[4][4] = {};
    const int fr = lane & 15, fq = (lane >> 4) * 8;
    const int srow = tid >> 2, sch = (tid & 3) * 8;

    for (int k0 = 0; k0 < K; k0 += 32) {
#pragma unroll
        for (int q = 0; q < 2; ++q) {
            int row = q * 64 + srow;
            gl_lds16(&A[(size_t)(m0 + row) * K + k0 + sch], &At[row * 32 + sch]);
            gl_lds16(&Bt[(size_t)(n0 + row) * K + k0 + sch], &Bl[row * 32 + sch]);
        }
        __syncthreads();
        bf16x8_t af[4], bf[4];
#pragma unroll
        for (int i = 0; i < 4; ++i) {
            af[i] = *(bf16x8_t*)&At[(wm + i * 16 + fr) * 32 + fq];
            bf[i] = *(bf16x8_t*)&Bl[(wn + i * 16 + fr) * 32 + fq];
        }
#pragma unroll
        for (int i = 0; i < 4; ++i)
#pragma unroll
            for (int j = 0; j < 4; ++j)
                acc[i][j] = __builtin_amdgcn_mfma_f32_16x16x32_bf16(af[i], bf[j], acc[i][j], 0, 0, 0);
        __syncthreads();
    }

    const int col = lane & 15, rbase = (lane >> 4) * 4;
#pragma unroll
    for (int i = 0; i < 4; ++i) {
#pragma unroll
        for (int j = 0; j < 4; ++j) {
#pragma unroll
            for (int r = 0; r < 4; ++r) {
                int m = m0 + wm + i * 16 + rbase + r;
                int n = n0 + wn + j * 16 + col;
                float v = acc[i][j][r] + bias[n];
                if (EPI == 0) {
                    ((__hip_bfloat16*)out0)[(size_t)m * 512 + n] = __float2bfloat16(v);
                } else if (EPI == 1) {
                    if (n < 512) {
                        float ep = __bfloat162float(((const __hip_bfloat16*)extra)[(size_t)m * 512 + n]);
                        ((__hip_bfloat16*)out0)[(size_t)m * 512 + n] =
                            __float2bfloat16(fmaf(v, sigmoidf_(ep), ep));
                    } else {
                        ((__hip_bfloat16*)out1)[(size_t)m * 512 + (n - 512)] =
                            __float2bfloat16(sigmoidf_(v));
                    }
                } else if (EPI == 2) {
                    if (n < 512)
                        ((__hip_bfloat16*)out0)[(size_t)m * 512 + n] = __float2bfloat16(v);
                    else
                        ((__hip_bfloat16*)out1)[(size_t)m * 512 + (n - 512)] =
                            __float2bfloat16(siluf_(v));
                } else {
                    float g = __bfloat162float(((const __hip_bfloat16*)extra)[(size_t)m * 512 + n]);
                    ((__hip_bfloat16*)out0)[(size_t)m * 512 + n] = __float2bfloat16(v * g);
                }
            }
        }
    }
}

// ---------------------------------------------------------------------------
// k_conv_scan: conv + x_dbl + dt + CHUNK-scan fused (round-8 winner, unchanged).
// ---------------------------------------------------------------------------
#define CHUNK 32
#define NCHUNK 128

__global__ __launch_bounds__(512) void k_conv_scan(
    const __hip_bfloat16* __restrict__ xm, const float* __restrict__ conv_w,
    const float* __restrict__ conv_b, const __hip_bfloat16* __restrict__ xpwT,
    const __hip_bfloat16* __restrict__ dtwT, const float* __restrict__ dt_b,
    const float* __restrict__ A_log,
    __hip_bfloat16* __restrict__ u_out, float* __restrict__ Bm,
    float* __restrict__ Cm, __hip_bfloat16* __restrict__ dt_out,
    float* __restrict__ hpart, float* __restrict__ dtsums)
{
    __shared__ __align__(16) ushort us_dts[CHUNK][512 + 8];
    __shared__ __align__(16) ushort adt[CHUNK][32 + 8];
    __shared__ float BsL[CHUNK * 16];
    __shared__ float CsL[CHUNK * 16];
    const int tid = threadIdx.x;
    const int wave = tid >> 6, lane = tid & 63;
    const int bl0 = blockIdx.x * CHUNK;
    const int l0 = bl0 & 4095;
    const int b = blockIdx.x >> 7;
    const int chunk = blockIdx.x & (NCHUNK - 1);
    const int fr = lane & 15, fq = (lane >> 4) * 8;
    const int col = lane & 15, rbase = (lane >> 4) * 4;

    float uarr[CHUNK];
    {
        const int d = tid;
        const float cw0 = conv_w[d * 4], cw1 = conv_w[d * 4 + 1];
        const float cw2 = conv_w[d * 4 + 2], cw3 = conv_w[d * 4 + 3];
        const float cb = conv_b[d];
        const ushort* xs = (const ushort*)xm;
        float x0 = (l0 >= 3) ? b2f(xs[(size_t)(bl0 - 3) * 512 + d]) : 0.f;
        float x1 = (l0 >= 2) ? b2f(xs[(size_t)(bl0 - 2) * 512 + d]) : 0.f;
        float x2 = (l0 >= 1) ? b2f(xs[(size_t)(bl0 - 1) * 512 + d]) : 0.f;
#pragma unroll
        for (int t = 0; t < CHUNK; ++t) {
            float x3 = b2f(xs[(size_t)(bl0 + t) * 512 + d]);
            float a = cb;
            a = fmaf(cw0, x0, a);
            a = fmaf(cw1, x1, a);
            a = fmaf(cw2, x2, a);
            a = fmaf(cw3, x3, a);
            float uv = siluf_(a);
            uarr[t] = uv;
            ushort ub = f2b(uv);
            us_dts[t][d] = ub;
            ((ushort*)u_out)[(size_t)(bl0 + t) * 512 + d] = ub;
            x0 = x1; x1 = x2; x2 = x3;
        }
    }
    __syncthreads();

    {
        const int mi = wave >> 2, n0w = (wave & 3) * 16;
        f32x4_t acc = {};
        const __hip_bfloat16* bp = xpwT + (size_t)(n0w + fr) * 512;
#pragma unroll
        for (int k0 = 0; k0 < 512; k0 += 32) {
            bf16x8_t af = *(bf16x8_t*)&us_dts[mi * 16 + fr][k0 + fq];
            bf16x8_t bf = *(const bf16x8_t*)&bp[k0 + fq];
            acc = __builtin_amdgcn_mfma_f32_16x16x32_bf16(af, bf, acc, 0, 0, 0);
        }
#pragma unroll
        for (int r = 0; r < 4; ++r) {
            int m = mi * 16 + rbase + r;
            int n = n0w + col;
            float v = acc[r];
            if (n < 32) {
                adt[m][n] = f2b(v);
            } else if (n < 48) {
                BsL[m * 16 + (n - 32)] = v;
                Bm[(size_t)(bl0 + m) * 16 + (n - 32)] = v;
            } else {
                CsL[m * 16 + (n - 48)] = v;
                Cm[(size_t)(bl0 + m) * 16 + (n - 48)] = v;
            }
        }
    }
    __syncthreads();

    {
        const int mi = wave >> 2;
        bf16x8_t af = *(bf16x8_t*)&adt[mi * 16 + fr][fq];
#pragma unroll
        for (int t = 0; t < 8; ++t) {
            int nt = (wave & 3) * 8 + t;
            bf16x8_t bf = *(const bf16x8_t*)&dtwT[(size_t)(nt * 16 + fr) * 32 + fq];
            f32x4_t acc = {};
            acc = __builtin_amdgcn_mfma_f32_16x16x32_bf16(af, bf, acc, 0, 0, 0);
#pragma unroll
            for (int r = 0; r < 4; ++r) {
                int m = mi * 16 + rbase + r;
                int n = nt * 16 + col;
                ushort dv = f2b(softplusf_(acc[r] + dt_b[n]));
                us_dts[m][n] = dv;
                ((ushort*)dt_out)[(size_t)(bl0 + m) * 512 + n] = dv;
            }
        }
    }
    __syncthreads();

    {
        const int d = tid;
        float Av[16];
#pragma unroll
        for (int n = 0; n < 16; n += 4) {
            float4 al = *(const float4*)&A_log[d * 16 + n];
            Av[n + 0] = -__expf(al.x);
            Av[n + 1] = -__expf(al.y);
            Av[n + 2] = -__expf(al.z);
            Av[n + 3] = -__expf(al.w);
        }
        float h[16] = {};
        float dtsum = 0.f;
#pragma unroll
        for (int t = 0; t < CHUNK; ++t) {
            float dtv = b2f(us_dts[t][d]);
            float dtu = dtv * uarr[t];
            dtsum += dtv;
            const float* Bt = &BsL[t * 16];
#pragma unroll
            for (int n = 0; n < 16; ++n)
                h[n] = fmaf(h[n], __expf(dtv * Av[n]), dtu * Bt[n]);
        }
        const size_t sidx = ((size_t)b * NCHUNK + chunk) * 512 + d;
        const size_t idx = sidx * 16;
#pragma unroll
        for (int n = 0; n < 16; n += 4)
            *(float4*)&hpart[idx + n] = make_float4(h[n], h[n + 1], h[n + 2], h[n + 3]);
        dtsums[sidx] = dtsum;
    }
}

__global__ __launch_bounds__(256) void k_scan_comb(
    const float* __restrict__ hpart, const float* __restrict__ dtsums,
    const float* __restrict__ A_log, float* __restrict__ h_in)
{
    const int gid = blockIdx.x * 256 + threadIdx.x;
    const int n = gid & 15;
    const int d = (gid >> 4) & 511;
    const int b = gid >> 13;
    const float Av = -__expf(A_log[d * 16 + n]);
    float h = 0.f;
    for (int c = 0; c < NCHUNK; ++c) {
        const size_t sidx = ((size_t)b * NCHUNK + c) * 512 + d;
        const size_t idx = sidx * 16 + n;
        h_in[idx] = h;
        h = fmaf(h, __expf(Av * dtsums[sidx]), hpart[idx]);
    }
}

__global__ __launch_bounds__(512) void k_scan_fin(
    const __hip_bfloat16* __restrict__ dt, const __hip_bfloat16* __restrict__ u,
    const float* __restrict__ Bmp, const float* __restrict__ Cmp,
    const float* __restrict__ A_log, const float* __restrict__ Dp,
    const __hip_bfloat16* __restrict__ zs, const float* __restrict__ h_in,
    __hip_bfloat16* __restrict__ yout)
{
    __shared__ float Bs[CHUNK * 16];
    __shared__ float Cs[CHUNK * 16];
    const int d = threadIdx.x;
    const int chunk = blockIdx.x & (NCHUNK - 1);
    const int b = blockIdx.x >> 7;
    const size_t row0 = (size_t)b * 4096 + (size_t)chunk * CHUNK;

    Bs[d] = Bmp[row0 * 16 + d];
    Cs[d] = Cmp[row0 * 16 + d];
    float Av[16];
#pragma unroll
    for (int n = 0; n < 16; n += 4) {
        float4 al = *(const float4*)&A_log[d * 16 + n];
        Av[n + 0] = -__expf(al.x);
        Av[n + 1] = -__expf(al.y);
        Av[n + 2] = -__expf(al.z);
        Av[n + 3] = -__expf(al.w);
    }
    const float Dv = Dp[d];
    float h[16];
    const size_t idx = (((size_t)b * NCHUNK + chunk) * 512 + d) * 16;
#pragma unroll
    for (int n = 0; n < 16; n += 4) {
        float4 hv = *(const float4*)&h_in[idx + n];
        h[n] = hv.x; h[n + 1] = hv.y; h[n + 2] = hv.z; h[n + 3] = hv.w;
    }
    __syncthreads();

    const ushort* dtp = (const ushort*)dt + row0 * 512 + d;
    const ushort* up = (const ushort*)u + row0 * 512 + d;
    const ushort* zp = (const ushort*)zs + row0 * 512 + d;
    __hip_bfloat16* yp = yout + row0 * 512 + d;
    for (int t = 0; t < CHUNK; ++t) {
        float dtv = b2f(dtp[(size_t)t * 512]);
        float uv = b2f(up[(size_t)t * 512]);
        float zv = b2f(zp[(size_t)t * 512]);
        float dtu = dtv * uv;
        const float* Bt = &Bs[t * 16];
        const float* Ct = &Cs[t * 16];
        float y = 0.f;
#pragma unroll
        for (int n = 0; n < 16; ++n) {
            h[n] = fmaf(h[n], __expf(dtv * Av[n]), dtu * Bt[n]);
            y = fmaf(h[n], Ct[n], y);
        }
        yp[(size_t)t * 512] = __float2bfloat16((y + uv * Dv) * zv);
    }
}

// ---------------------------------------------------------------------------
// k_out_ln: final GEMM (M-tile 64, N=256, K=512) + out_b + residual +
// LayerNorm over C=256 + transposed write. Async LDS staging.
// ---------------------------------------------------------------------------
__global__ __launch_bounds__(256) void k_out_ln(
    const __hip_bfloat16* __restrict__ A, const __hip_bfloat16* __restrict__ Bt,
    const float* __restrict__ bias, const __hip_bfloat16* __restrict__ decL,
    const float* __restrict__ ln_g, const float* __restrict__ ln_b,
    float* __restrict__ outp)
{
    __shared__ ushort At[64 * 32];
    __shared__ ushort Bl[256 * 32];
    __shared__ float red[4][64][2];
    __shared__ float lmu[64], lsc[64];
    const int tid = threadIdx.x;
    const int wave = tid >> 6, lane = tid & 63;
    const int m0 = blockIdx.x * 64;
    const int wn = wave * 64;
    f32x4_t acc[4][4] = {};
    const int fr = lane & 15, fq = (lane >> 4) * 8;
    const int srow = tid >> 2, sch = (tid & 3) * 8;

    for (int k0 = 0; k0 < 512; k0 += 32) {
        gl_lds16(&A[(size_t)(m0 + srow) * 512 + k0 + sch], &At[srow * 32 + sch]);
#pragma unroll
        for (int q = 0; q < 4; ++q) {
            int row = q * 64 + srow;
            gl_lds16(&Bt[(size_t)row * 512 + k0 + sch], &Bl[row * 32 + sch]);
        }
        __syncthreads();
        bf16x8_t af[4], bf[4];
#pragma unroll
        for (int i = 0; i < 4; ++i) {
            af[i] = *(bf16x8_t*)&At[(i * 16 + fr) * 32 + fq];
            bf[i] = *(bf16x8_t*)&Bl[(wn + i * 16 + fr) * 32 + fq];
        }
#pragma unroll
        for (int i = 0; i < 4; ++i)
#pragma unroll
            for (int j = 0; j < 4; ++j)
                acc[i][j] = __builtin_amdgcn_mfma_f32_16x16x32_bf16(af[i], bf[j], acc[i][j], 0, 0, 0);
        __syncthreads();
    }

    const int col = lane & 15, rbase = (lane >> 4) * 4;
#pragma unroll
    for (int i = 0; i < 4; ++i) {
#pragma unroll
        for (int r = 0; r < 4; ++r) {
            int ml = i * 16 + rbase + r;
            int m = m0 + ml;
            float s = 0.f, sq = 0.f;
#pragma unroll
            for (int j = 0; j < 4; ++j) {
                int n = wn + j * 16 + col;
                float dv = b2f(((const ushort*)decL)[(size_t)m * 256 + n]);
                float v = acc[i][j][r] + bias[n] + dv;
                acc[i][j][r] = v;
                s += v;
                sq = fmaf(v, v, sq);
            }
            s += __shfl_xor(s, 1);  sq += __shfl_xor(sq, 1);
            s += __shfl_xor(s, 2);  sq += __shfl_xor(sq, 2);
            s += __shfl_xor(s, 4);  sq += __shfl_xor(sq, 4);
            s += __shfl_xor(s, 8);  sq += __shfl_xor(sq, 8);
            if (col == 0) { red[wave][ml][0] = s; red[wave][ml][1] = sq; }
        }
    }
    __syncthreads();
    if (tid < 64) {
        float s  = red[0][tid][0] + red[1][tid][0] + red[2][tid][0] + red[3][tid][0];
        float sq = red[0][tid][1] + red[1][tid][1] + red[2][tid][1] + red[3][tid][1];
        float mu = s * (1.0f / 256.0f);
        float var = sq * (1.0f / 256.0f) - mu * mu;
        lmu[tid] = mu;
        lsc[tid] = rsqrtf(var + 1e-5f);
    }
    __syncthreads();
    const int bb = m0 >> 12;
    const int lpos0 = m0 & 4095;
#pragma unroll
    for (int i = 0; i < 4; ++i) {
#pragma unroll
        for (int r = 0; r < 4; ++r) {
            int ml = i * 16 + rbase + r;
            float mu = lmu[ml], sc = lsc[ml];
#pragma unroll
            for (int j = 0; j < 4; ++j) {
                int n = wn + j * 16 + col;
                float v = (acc[i][j][r] - mu) * sc * ln_g[n] + ln_b[n];
                outp[(size_t)bb * (256 * 4096) + (size_t)n * 4096 + lpos0 + ml] = v;
            }
        }
    }
}

// ---------------------------------------------------------------------------
extern "C" void kernel_launch(void* const* d_in, const int* in_sizes, int n_in,
                              void* d_out, int out_size, void* d_ws, size_t ws_size,
                              hipStream_t stream)
{
    const float* decoder_feat = (const float*)d_in[0];
    const float* encoder_feat = (const float*)d_in[1];
    const float* dec_w = (const float*)d_in[2];
    const float* dec_b = (const float*)d_in[3];
    const float* enc_w = (const float*)d_in[4];
    const float* enc_b = (const float*)d_in[5];
    const float* out_w = (const float*)d_in[6];
    const float* out_b = (const float*)d_in[7];
    const float* ln_g = (const float*)d_in[8];
    const float* ln_bb = (const float*)d_in[9];
    const float* in_w = (const float*)d_in[10];
    const float* in_b = (const float*)d_in[11];
    const float* conv_w = (const float*)d_in[12];
    const float* conv_b = (const float*)d_in[13];
    const float* x_proj_w = (const float*)d_in[14];
    const float* dt_w = (const float*)d_in[15];
    const float* dt_b = (const float*)d_in[16];
    const float* A_log = (const float*)d_in[17];
    const float* D_param = (const float*)d_in[18];
    const float* m_out_w = (const float*)d_in[19];
    const float* m_out_b = (const float*)d_in[20];

    float* outp = (float*)d_out;
    char* ws = (char*)d_ws;
    const size_t MB = 1024ull * 1024;
    __hip_bfloat16* decL     = (__hip_bfloat16*)(ws + 0 * MB);    // 4 MB
    __hip_bfloat16* encL     = (__hip_bfloat16*)(ws + 4 * MB);    // 4 MB
    __hip_bfloat16* dec_wT   = (__hip_bfloat16*)(ws + 8 * MB);
    __hip_bfloat16* enc_wT   = (__hip_bfloat16*)(ws + 9 * MB);
    __hip_bfloat16* in_wT    = (__hip_bfloat16*)(ws + 10 * MB);
    __hip_bfloat16* m_out_wT = (__hip_bfloat16*)(ws + 11 * MB);
    __hip_bfloat16* out_wT   = (__hip_bfloat16*)(ws + 12 * MB);
    __hip_bfloat16* xpwT     = (__hip_bfloat16*)(ws + 12 * MB + 262144);
    __hip_bfloat16* dtwT     = (__hip_bfloat16*)(ws + 12 * MB + 262144 + 65536);
    __hip_bfloat16* enc_pb   = (__hip_bfloat16*)(ws + 13 * MB);   // 8 MB; reused: hpart
    __hip_bfloat16* combined = (__hip_bfloat16*)(ws + 29 * MB);   // 8 MB; reused: y
    __hip_bfloat16* gate_sig = (__hip_bfloat16*)(ws + 37 * MB);   // 8 MB
    __hip_bfloat16* xm       = (__hip_bfloat16*)(ws + 53 * MB);   // 8 MB; reused: h_in, gated
    __hip_bfloat16* z_silu   = (__hip_bfloat16*)(ws + 61 * MB);   // 8 MB
    __hip_bfloat16* u_buf    = (__hip_bfloat16*)(ws + 69 * MB);   // 8 MB
    __hip_bfloat16* dt_buf   = (__hip_bfloat16*)(ws + 77 * MB);   // 8 MB (bf16)
    float* Bm                = (float*)(ws + 93 * MB);            // 0.5 MB
    float* Cm                = (float*)(ws + 93 * MB + 524288);   // 0.5 MB
    // scan scratch (dead-slot reuse; stream-ordered, safe)
    float* hpart  = (float*)(ws + 13 * MB);      // enc_pb dead after bgemm<1>
    float* dtsums = (float*)(ws + 21 * MB);      // 0.5 MB
    float* h_in   = (float*)xm;                  // xm dead after k_conv_scan
    __hip_bfloat16* y_buf = combined;            // combined dead after bgemm<2>
    __hip_bfloat16* gated = xm;                  // written after scan_fin reads h_in

    k_prep<<<6336, 256, 0, stream>>>(
        dec_w, enc_w, in_w, m_out_w, out_w, x_proj_w, dt_w,
        decoder_feat, encoder_feat,
        dec_wT, enc_wT, in_wT, m_out_wT, out_wT, xpwT, dtwT, decL, encL);
    bgemm<0, 256><<<dim3(4, 64), 256, 0, stream>>>(
        encL, enc_wT, enc_b, enc_pb, nullptr, nullptr);
    bgemm<1, 256><<<dim3(8, 64), 256, 0, stream>>>(
        decL, dec_wT, dec_b, combined, gate_sig, enc_pb);
    bgemm<2, 512><<<dim3(8, 64), 256, 0, stream>>>(
        combined, in_wT, in_b, xm, z_silu, nullptr);
    k_conv_scan<<<2 * NCHUNK, 512, 0, stream>>>(
        xm, conv_w, conv_b, xpwT, dtwT, dt_b, A_log,
        u_buf, Bm, Cm, dt_buf, hpart, dtsums);
    k_scan_comb<<<64, 256, 0, stream>>>(hpart, dtsums, A_log, h_in);
    k_scan_fin<<<2 * NCHUNK, 512, 0, stream>>>(
        dt_buf, u_buf, Bm, Cm, A_log, D_param, z_silu, h_in, y_buf);
    bgemm<3, 512><<<dim3(4, 64), 256, 0, stream>>>(
        y_buf, m_out_wT, m_out_b, gated, nullptr, gate_sig);
    k_out_ln<<<128, 256, 0, stream>>>(
        gated, out_wT, out_b, decL, ln_g, ln_bb, outp);
}

// Round 10
// 295.932 us; speedup vs baseline: 1.4159x; 1.4159x over previous
//
#include <hip/hip_runtime.h>
#include <hip/hip_bf16.h>

typedef __bf16 bf16x8_t __attribute__((ext_vector_type(8)));
typedef float f32x4_t __attribute__((ext_vector_type(4)));

__device__ __forceinline__ float sigmoidf_(float x) { return 1.0f / (1.0f + __expf(-x)); }
__device__ __forceinline__ float siluf_(float x) { return x * sigmoidf_(x); }
__device__ __forceinline__ float softplusf_(float x) {
    return fmaxf(x, 0.0f) + log1pf(__expf(-fabsf(x)));
}
__device__ __forceinline__ float b2f(ushort u) { return __uint_as_float(((unsigned)u) << 16); }
__device__ __forceinline__ ushort f2b(float f) {
    return (ushort)__bfloat16_as_ushort(__float2bfloat16(f));
}
// NOTE: round-9 tried __builtin_amdgcn_global_load_lds staging here -> 285->419us
// REGRESSION. Direct-to-LDS cannot issue until the LDS tile is free (post-
// barrier), killing the compiler's cross-barrier prefetch of next-tile loads.
// VGPR round-trip staging restored.

// ---------------------------------------------------------------------------
// k_prep: (blocks 0..5311) cast+transpose weights fp32 [K][N] -> bf16 [N][K];
//         (blocks 5312..6335) transpose inputs (b,c,l) fp32 -> (b,l,c) bf16.
// ---------------------------------------------------------------------------
__global__ __launch_bounds__(256) void k_prep(
    const float* __restrict__ dec_w, const float* __restrict__ enc_w,
    const float* __restrict__ in_w, const float* __restrict__ m_out_w,
    const float* __restrict__ out_w, const float* __restrict__ x_proj_w,
    const float* __restrict__ dt_w,
    const float* __restrict__ dec, const float* __restrict__ enc,
    __hip_bfloat16* __restrict__ dec_wT, __hip_bfloat16* __restrict__ enc_wT,
    __hip_bfloat16* __restrict__ in_wT, __hip_bfloat16* __restrict__ m_out_wT,
    __hip_bfloat16* __restrict__ out_wT, __hip_bfloat16* __restrict__ xpwT,
    __hip_bfloat16* __restrict__ dtwT,
    __hip_bfloat16* __restrict__ decL, __hip_bfloat16* __restrict__ encL)
{
    __shared__ float tile[64][65];
    if (blockIdx.x < 5312) {
        int gid = blockIdx.x * 256 + threadIdx.x;
        const float* src; __hip_bfloat16* dst; int lk, N, idx;
        if (gid < 262144)       { src = dec_w;    dst = dec_wT;   lk = 8; N = 1024; idx = gid; }
        else if (gid < 393216)  { src = enc_w;    dst = enc_wT;   lk = 8; N = 512;  idx = gid - 262144; }
        else if (gid < 917504)  { src = in_w;     dst = in_wT;    lk = 9; N = 1024; idx = gid - 393216; }
        else if (gid < 1179648) { src = m_out_w;  dst = m_out_wT; lk = 9; N = 512;  idx = gid - 917504; }
        else if (gid < 1310720) { src = out_w;    dst = out_wT;   lk = 9; N = 256;  idx = gid - 1179648; }
        else if (gid < 1343488) { src = x_proj_w; dst = xpwT;     lk = 9; N = 64;   idx = gid - 1310720; }
        else                    { src = dt_w;     dst = dtwT;     lk = 5; N = 512;  idx = gid - 1343488; }
        int K = 1 << lk;
        int n = idx >> lk, k = idx & (K - 1);
        dst[idx] = __float2bfloat16(src[(size_t)k * N + n]);
        return;
    }
    const int bid = blockIdx.x - 5312;
    const int t = threadIdx.x;
    const int ct = bid & 3;
    const int lt = (bid >> 2) & 63;
    const int sel = bid >> 8;
    const int b = sel & 1, ten = sel >> 1;
    const float* src = ten ? enc : dec;
    __hip_bfloat16* dst = ten ? encL : decL;
    const size_t ibase = (size_t)b * 256 * 4096 + (size_t)(ct * 64) * 4096 + (size_t)lt * 64;
#pragma unroll
    for (int i = 0; i < 16; ++i) {
        int c = i * 4 + (t >> 6), l = t & 63;
        tile[c][l] = src[ibase + (size_t)c * 4096 + l];
    }
    __syncthreads();
    const size_t obase = ((size_t)b * 4096 + (size_t)lt * 64) * 256 + ct * 64;
#pragma unroll
    for (int i = 0; i < 16; ++i) {
        int l = i * 4 + (t >> 6), c = t & 63;
        dst[obase + (size_t)l * 256 + c] = __float2bfloat16(tile[c][l]);
    }
}

// ---------------------------------------------------------------------------
// bf16 MFMA GEMM (128x128 tile, BK=32, 4 waves of 64x64). VGPR-staged.
// EPI 0: enc_p bf16 | EPI 1: combined bf16 + sigmoid(gate) bf16 (extra=enc_p)
// EPI 2: xm/silu(z) bf16 | EPI 3: v * extra (gate_sig bf16)
// ---------------------------------------------------------------------------
template <int EPI, int K>
__global__ __launch_bounds__(256) void bgemm(
    const __hip_bfloat16* __restrict__ A, const __hip_bfloat16* __restrict__ Bt,
    const float* __restrict__ bias, void* __restrict__ out0,
    void* __restrict__ out1, const void* __restrict__ extra)
{
    __shared__ ushort At[128 * 32];
    __shared__ ushort Bl[128 * 32];
    const int tid = threadIdx.x;
    const int wave = tid >> 6, lane = tid & 63;
    const int n0 = blockIdx.x * 128, m0 = blockIdx.y * 128;
    const int wm = (wave >> 1) * 64, wn = (wave & 1) * 64;
    f32x4_t acc[4][4] = {};
    const int fr = lane & 15, fq = (lane >> 4) * 8;

    for (int k0 = 0; k0 < K; k0 += 32) {
#pragma unroll
        for (int q = 0; q < 2; ++q) {
            int idx = q * 256 + tid;
            int row = idx >> 2, ch = (idx & 3) * 8;
            uint4 va = *(const uint4*)&A[(size_t)(m0 + row) * K + k0 + ch];
            uint4 vb = *(const uint4*)&Bt[(size_t)(n0 + row) * K + k0 + ch];
            *(uint4*)&At[row * 32 + ch] = va;
            *(uint4*)&Bl[row * 32 + ch] = vb;
        }
        __syncthreads();
        bf16x8_t af[4], bf[4];
#pragma unroll
        for (int i = 0; i < 4; ++i) {
            af[i] = *(bf16x8_t*)&At[(wm + i * 16 + fr) * 32 + fq];
            bf[i] = *(bf16x8_t*)&Bl[(wn + i * 16 + fr) * 32 + fq];
        }
#pragma unroll
        for (int i = 0; i < 4; ++i)
#pragma unroll
            for (int j = 0; j < 4; ++j)
                acc[i][j] = __builtin_amdgcn_mfma_f32_16x16x32_bf16(af[i], bf[j], acc[i][j], 0, 0, 0);
        __syncthreads();
    }

    const int col = lane & 15, rbase = (lane >> 4) * 4;
#pragma unroll
    for (int i = 0; i < 4; ++i) {
#pragma unroll
        for (int j = 0; j < 4; ++j) {
#pragma unroll
            for (int r = 0; r < 4; ++r) {
                int m = m0 + wm + i * 16 + rbase + r;
                int n = n0 + wn + j * 16 + col;
                float v = acc[i][j][r] + bias[n];
                if (EPI == 0) {
                    ((__hip_bfloat16*)out0)[(size_t)m * 512 + n] = __float2bfloat16(v);
                } else if (EPI == 1) {
                    if (n < 512) {
                        float ep = __bfloat162float(((const __hip_bfloat16*)extra)[(size_t)m * 512 + n]);
                        ((__hip_bfloat16*)out0)[(size_t)m * 512 + n] =
                            __float2bfloat16(fmaf(v, sigmoidf_(ep), ep));
                    } else {
                        ((__hip_bfloat16*)out1)[(size_t)m * 512 + (n - 512)] =
                            __float2bfloat16(sigmoidf_(v));
                    }
                } else if (EPI == 2) {
                    if (n < 512)
                        ((__hip_bfloat16*)out0)[(size_t)m * 512 + n] = __float2bfloat16(v);
                    else
                        ((__hip_bfloat16*)out1)[(size_t)m * 512 + (n - 512)] =
                            __float2bfloat16(siluf_(v));
                } else {
                    float g = __bfloat162float(((const __hip_bfloat16*)extra)[(size_t)m * 512 + n]);
                    ((__hip_bfloat16*)out0)[(size_t)m * 512 + n] = __float2bfloat16(v * g);
                }
            }
        }
    }
}

// ---------------------------------------------------------------------------
// k_conv_scan<MODE>: conv + x_dbl + dt (phases 1-3, LDS/regs only -- u/dt/B/C
// never hit HBM) + phase 4:
//   MODE 0: chunk partial scan -> hpart + dtsums.
//   MODE 1: load h_in, full scan + y = (sum h*C + u*D) * silu(z) -> yout.
// Block = 32 rows (one chunk), 512 threads (8 waves), 256 blocks.
// ---------------------------------------------------------------------------
#define CHUNK 32
#define NCHUNK 128

template <int MODE>
__global__ __launch_bounds__(512) void k_conv_scan(
    const __hip_bfloat16* __restrict__ xm, const float* __restrict__ conv_w,
    const float* __restrict__ conv_b, const __hip_bfloat16* __restrict__ xpwT,
    const __hip_bfloat16* __restrict__ dtwT, const float* __restrict__ dt_b,
    const float* __restrict__ A_log,
    float* __restrict__ hpart, float* __restrict__ dtsums,
    const float* __restrict__ Dp, const __hip_bfloat16* __restrict__ zs,
    const float* __restrict__ h_in, __hip_bfloat16* __restrict__ yout)
{
    __shared__ __align__(16) ushort us_dts[CHUNK][512 + 8];  // u, then dt (aliased)
    __shared__ __align__(16) ushort adt[CHUNK][32 + 8];
    __shared__ float BsL[CHUNK * 16];
    __shared__ float CsL[CHUNK * 16];
    const int tid = threadIdx.x;
    const int wave = tid >> 6, lane = tid & 63;
    const int bl0 = blockIdx.x * CHUNK;
    const int l0 = bl0 & 4095;
    const int b = blockIdx.x >> 7;
    const int chunk = blockIdx.x & (NCHUNK - 1);
    const int fr = lane & 15, fq = (lane >> 4) * 8;
    const int col = lane & 15, rbase = (lane >> 4) * 4;

    // ---- phase 1: depthwise conv + silu; thread d keeps u[t] in registers
    float uarr[CHUNK];
    {
        const int d = tid;
        const float cw0 = conv_w[d * 4], cw1 = conv_w[d * 4 + 1];
        const float cw2 = conv_w[d * 4 + 2], cw3 = conv_w[d * 4 + 3];
        const float cb = conv_b[d];
        const ushort* xs = (const ushort*)xm;
        float x0 = (l0 >= 3) ? b2f(xs[(size_t)(bl0 - 3) * 512 + d]) : 0.f;
        float x1 = (l0 >= 2) ? b2f(xs[(size_t)(bl0 - 2) * 512 + d]) : 0.f;
        float x2 = (l0 >= 1) ? b2f(xs[(size_t)(bl0 - 1) * 512 + d]) : 0.f;
#pragma unroll
        for (int t = 0; t < CHUNK; ++t) {
            float x3 = b2f(xs[(size_t)(bl0 + t) * 512 + d]);
            float a = cb;
            a = fmaf(cw0, x0, a);
            a = fmaf(cw1, x1, a);
            a = fmaf(cw2, x2, a);
            a = fmaf(cw3, x3, a);
            float uv = siluf_(a);
            uarr[t] = uv;
            us_dts[t][d] = f2b(uv);
            x0 = x1; x1 = x2; x2 = x3;
        }
    }
    __syncthreads();

    // ---- phase 2: x_dbl (M=32,N=64,K=512). wave w: m-tile w>>2, n-tile w&3
    {
        const int mi = wave >> 2, n0w = (wave & 3) * 16;
        f32x4_t acc = {};
        const __hip_bfloat16* bp = xpwT + (size_t)(n0w + fr) * 512;
#pragma unroll
        for (int k0 = 0; k0 < 512; k0 += 32) {
            bf16x8_t af = *(bf16x8_t*)&us_dts[mi * 16 + fr][k0 + fq];
            bf16x8_t bf = *(const bf16x8_t*)&bp[k0 + fq];
            acc = __builtin_amdgcn_mfma_f32_16x16x32_bf16(af, bf, acc, 0, 0, 0);
        }
#pragma unroll
        for (int r = 0; r < 4; ++r) {
            int m = mi * 16 + rbase + r;
            int n = n0w + col;
            float v = acc[r];
            if (n < 32)      adt[m][n] = f2b(v);
            else if (n < 48) BsL[m * 16 + (n - 32)] = v;
            else             CsL[m * 16 + (n - 48)] = v;
        }
    }
    __syncthreads();   // us reads done -> dt may overwrite

    // ---- phase 3: dt (M=32,N=512,K=32). wave w: m-tile w>>2, n-tiles (w&3)*8..
    {
        const int mi = wave >> 2;
        bf16x8_t af = *(bf16x8_t*)&adt[mi * 16 + fr][fq];
#pragma unroll
        for (int t = 0; t < 8; ++t) {
            int nt = (wave & 3) * 8 + t;
            bf16x8_t bf = *(const bf16x8_t*)&dtwT[(size_t)(nt * 16 + fr) * 32 + fq];
            f32x4_t acc = {};
            acc = __builtin_amdgcn_mfma_f32_16x16x32_bf16(af, bf, acc, 0, 0, 0);
#pragma unroll
            for (int r = 0; r < 4; ++r) {
                int m = mi * 16 + rbase + r;
                int n = nt * 16 + col;
                us_dts[m][n] = f2b(softplusf_(acc[r] + dt_b[n]));
            }
        }
    }
    __syncthreads();

    // ---- phase 4: chunk scan (thread d; u in regs, dt/B/C in LDS)
    {
        const int d = tid;
        float Av[16];
#pragma unroll
        for (int n = 0; n < 16; n += 4) {
            float4 al = *(const float4*)&A_log[d * 16 + n];
            Av[n + 0] = -__expf(al.x);
            Av[n + 1] = -__expf(al.y);
            Av[n + 2] = -__expf(al.z);
            Av[n + 3] = -__expf(al.w);
        }
        const size_t sidx = ((size_t)b * NCHUNK + chunk) * 512 + d;
        const size_t idx = sidx * 16;
        if (MODE == 0) {
            float h[16] = {};
            float dtsum = 0.f;
#pragma unroll
            for (int t = 0; t < CHUNK; ++t) {
                float dtv = b2f(us_dts[t][d]);
                float dtu = dtv * uarr[t];
                dtsum += dtv;
                const float* Bt = &BsL[t * 16];
#pragma unroll
                for (int n = 0; n < 16; ++n)
                    h[n] = fmaf(h[n], __expf(dtv * Av[n]), dtu * Bt[n]);
            }
#pragma unroll
            for (int n = 0; n < 16; n += 4)
                *(float4*)&hpart[idx + n] = make_float4(h[n], h[n + 1], h[n + 2], h[n + 3]);
            dtsums[sidx] = dtsum;
        } else {
            const float Dv = Dp[d];
            float h[16];
#pragma unroll
            for (int n = 0; n < 16; n += 4) {
                float4 hv = *(const float4*)&h_in[idx + n];
                h[n] = hv.x; h[n + 1] = hv.y; h[n + 2] = hv.z; h[n + 3] = hv.w;
            }
            const size_t row0 = (size_t)b * 4096 + (size_t)chunk * CHUNK;
            const ushort* zp = (const ushort*)zs + row0 * 512 + d;
            ushort* yp = (ushort*)yout + row0 * 512 + d;
#pragma unroll 4
            for (int t = 0; t < CHUNK; ++t) {
                float dtv = b2f(us_dts[t][d]);
                float uv = uarr[t];
                float zv = b2f(zp[(size_t)t * 512]);
                float dtu = dtv * uv;
                const float* Bt = &BsL[t * 16];
                const float* Ct = &CsL[t * 16];
                float y = 0.f;
#pragma unroll
                for (int n = 0; n < 16; ++n) {
                    h[n] = fmaf(h[n], __expf(dtv * Av[n]), dtu * Bt[n]);
                    y = fmaf(h[n], Ct[n], y);
                }
                yp[(size_t)t * 512] = f2b((y + uv * Dv) * zv);
            }
        }
    }
}

__global__ __launch_bounds__(256) void k_scan_comb(
    const float* __restrict__ hpart, const float* __restrict__ dtsums,
    const float* __restrict__ A_log, float* __restrict__ h_in)
{
    const int gid = blockIdx.x * 256 + threadIdx.x;
    const int n = gid & 15;
    const int d = (gid >> 4) & 511;
    const int b = gid >> 13;
    const float Av = -__expf(A_log[d * 16 + n]);
    float h = 0.f;
    for (int c = 0; c < NCHUNK; ++c) {
        const size_t sidx = ((size_t)b * NCHUNK + c) * 512 + d;
        const size_t idx = sidx * 16 + n;
        h_in[idx] = h;
        h = fmaf(h, __expf(Av * dtsums[sidx]), hpart[idx]);
    }
}

// ---------------------------------------------------------------------------
// k_out_ln: final GEMM (M-tile 64, N=256, K=512) + out_b + residual +
// LayerNorm over C=256 + transposed write. 128 blocks x 256 threads.
// ---------------------------------------------------------------------------
__global__ __launch_bounds__(256) void k_out_ln(
    const __hip_bfloat16* __restrict__ A, const __hip_bfloat16* __restrict__ Bt,
    const float* __restrict__ bias, const __hip_bfloat16* __restrict__ decL,
    const float* __restrict__ ln_g, const float* __restrict__ ln_b,
    float* __restrict__ outp)
{
    __shared__ ushort At[64 * 32];
    __shared__ ushort Bl[256 * 32];
    __shared__ float red[4][64][2];
    __shared__ float lmu[64], lsc[64];
    const int tid = threadIdx.x;
    const int wave = tid >> 6, lane = tid & 63;
    const int m0 = blockIdx.x * 64;
    const int wn = wave * 64;
    f32x4_t acc[4][4] = {};
    const int fr = lane & 15, fq = (lane >> 4) * 8;

    for (int k0 = 0; k0 < 512; k0 += 32) {
        {
            int row = tid >> 2, ch = (tid & 3) * 8;
            *(uint4*)&At[row * 32 + ch] = *(const uint4*)&A[(size_t)(m0 + row) * 512 + k0 + ch];
        }
#pragma unroll
        for (int q = 0; q < 4; ++q) {
            int idx = q * 256 + tid;
            int row = idx >> 2, ch = (idx & 3) * 8;
            *(uint4*)&Bl[row * 32 + ch] = *(const uint4*)&Bt[(size_t)row * 512 + k0 + ch];
        }
        __syncthreads();
        bf16x8_t af[4], bf[4];
#pragma unroll
        for (int i = 0; i < 4; ++i) {
            af[i] = *(bf16x8_t*)&At[(i * 16 + fr) * 32 + fq];
            bf[i] = *(bf16x8_t*)&Bl[(wn + i * 16 + fr) * 32 + fq];
        }
#pragma unroll
        for (int i = 0; i < 4; ++i)
#pragma unroll
            for (int j = 0; j < 4; ++j)
                acc[i][j] = __builtin_amdgcn_mfma_f32_16x16x32_bf16(af[i], bf[j], acc[i][j], 0, 0, 0);
        __syncthreads();
    }

    const int col = lane & 15, rbase = (lane >> 4) * 4;
#pragma unroll
    for (int i = 0; i < 4; ++i) {
#pragma unroll
        for (int r = 0; r < 4; ++r) {
            int ml = i * 16 + rbase + r;
            int m = m0 + ml;
            float s = 0.f, sq = 0.f;
#pragma unroll
            for (int j = 0; j < 4; ++j) {
                int n = wn + j * 16 + col;
                float dv = b2f(((const ushort*)decL)[(size_t)m * 256 + n]);
                float v = acc[i][j][r] + bias[n] + dv;
                acc[i][j][r] = v;
                s += v;
                sq = fmaf(v, v, sq);
            }
            s += __shfl_xor(s, 1);  sq += __shfl_xor(sq, 1);
            s += __shfl_xor(s, 2);  sq += __shfl_xor(sq, 2);
            s += __shfl_xor(s, 4);  sq += __shfl_xor(sq, 4);
            s += __shfl_xor(s, 8);  sq += __shfl_xor(sq, 8);
            if (col == 0) { red[wave][ml][0] = s; red[wave][ml][1] = sq; }
        }
    }
    __syncthreads();
    if (tid < 64) {
        float s  = red[0][tid][0] + red[1][tid][0] + red[2][tid][0] + red[3][tid][0];
        float sq = red[0][tid][1] + red[1][tid][1] + red[2][tid][1] + red[3][tid][1];
        float mu = s * (1.0f / 256.0f);
        float var = sq * (1.0f / 256.0f) - mu * mu;
        lmu[tid] = mu;
        lsc[tid] = rsqrtf(var + 1e-5f);
    }
    __syncthreads();
    const int bb = m0 >> 12;
    const int lpos0 = m0 & 4095;
#pragma unroll
    for (int i = 0; i < 4; ++i) {
#pragma unroll
        for (int r = 0; r < 4; ++r) {
            int ml = i * 16 + rbase + r;
            float mu = lmu[ml], sc = lsc[ml];
#pragma unroll
            for (int j = 0; j < 4; ++j) {
                int n = wn + j * 16 + col;
                float v = (acc[i][j][r] - mu) * sc * ln_g[n] + ln_b[n];
                outp[(size_t)bb * (256 * 4096) + (size_t)n * 4096 + lpos0 + ml] = v;
            }
        }
    }
}

// ---------------------------------------------------------------------------
extern "C" void kernel_launch(void* const* d_in, const int* in_sizes, int n_in,
                              void* d_out, int out_size, void* d_ws, size_t ws_size,
                              hipStream_t stream)
{
    const float* decoder_feat = (const float*)d_in[0];
    const float* encoder_feat = (const float*)d_in[1];
    const float* dec_w = (const float*)d_in[2];
    const float* dec_b = (const float*)d_in[3];
    const float* enc_w = (const float*)d_in[4];
    const float* enc_b = (const float*)d_in[5];
    const float* out_w = (const float*)d_in[6];
    const float* out_b = (const float*)d_in[7];
    const float* ln_g = (const float*)d_in[8];
    const float* ln_bb = (const float*)d_in[9];
    const float* in_w = (const float*)d_in[10];
    const float* in_b = (const float*)d_in[11];
    const float* conv_w = (const float*)d_in[12];
    const float* conv_b = (const float*)d_in[13];
    const float* x_proj_w = (const float*)d_in[14];
    const float* dt_w = (const float*)d_in[15];
    const float* dt_b = (const float*)d_in[16];
    const float* A_log = (const float*)d_in[17];
    const float* D_param = (const float*)d_in[18];
    const float* m_out_w = (const float*)d_in[19];
    const float* m_out_b = (const float*)d_in[20];

    float* outp = (float*)d_out;
    char* ws = (char*)d_ws;
    const size_t MB = 1024ull * 1024;
    __hip_bfloat16* decL     = (__hip_bfloat16*)(ws + 0 * MB);    // 4 MB
    __hip_bfloat16* encL     = (__hip_bfloat16*)(ws + 4 * MB);    // 4 MB
    __hip_bfloat16* dec_wT   = (__hip_bfloat16*)(ws + 8 * MB);
    __hip_bfloat16* enc_wT   = (__hip_bfloat16*)(ws + 9 * MB);
    __hip_bfloat16* in_wT    = (__hip_bfloat16*)(ws + 10 * MB);
    __hip_bfloat16* m_out_wT = (__hip_bfloat16*)(ws + 11 * MB);
    __hip_bfloat16* out_wT   = (__hip_bfloat16*)(ws + 12 * MB);
    __hip_bfloat16* xpwT     = (__hip_bfloat16*)(ws + 12 * MB + 262144);
    __hip_bfloat16* dtwT     = (__hip_bfloat16*)(ws + 12 * MB + 262144 + 65536);
    __hip_bfloat16* enc_pb   = (__hip_bfloat16*)(ws + 13 * MB);   // 8 MB; reused: hpart
    __hip_bfloat16* combined = (__hip_bfloat16*)(ws + 29 * MB);   // 8 MB; reused: y
    __hip_bfloat16* gate_sig = (__hip_bfloat16*)(ws + 37 * MB);   // 8 MB
    __hip_bfloat16* xm       = (__hip_bfloat16*)(ws + 53 * MB);   // 8 MB; LIVE through
                                                                  // k_conv_scan<1> (recompute)
    __hip_bfloat16* z_silu   = (__hip_bfloat16*)(ws + 61 * MB);   // 8 MB
    __hip_bfloat16* gated    = (__hip_bfloat16*)(ws + 69 * MB);   // 8 MB (old u_buf slot)
    float* h_in              = (float*)(ws + 77 * MB);            // 8 MB (old dt_buf slot)
    // scan scratch (dead-slot reuse; stream-ordered, safe)
    float* hpart  = (float*)(ws + 13 * MB);      // enc_pb dead after bgemm<1>
    float* dtsums = (float*)(ws + 21 * MB);      // 0.5 MB
    __hip_bfloat16* y_buf = combined;            // combined dead after bgemm<2>

    k_prep<<<6336, 256, 0, stream>>>(
        dec_w, enc_w, in_w, m_out_w, out_w, x_proj_w, dt_w,
        decoder_feat, encoder_feat,
        dec_wT, enc_wT, in_wT, m_out_wT, out_wT, xpwT, dtwT, decL, encL);
    bgemm<0, 256><<<dim3(4, 64), 256, 0, stream>>>(
        encL, enc_wT, enc_b, enc_pb, nullptr, nullptr);
    bgemm<1, 256><<<dim3(8, 64), 256, 0, stream>>>(
        decL, dec_wT, dec_b, combined, gate_sig, enc_pb);
    bgemm<2, 512><<<dim3(8, 64), 256, 0, stream>>>(
        combined, in_wT, in_b, xm, z_silu, nullptr);
    k_conv_scan<0><<<2 * NCHUNK, 512, 0, stream>>>(
        xm, conv_w, conv_b, xpwT, dtwT, dt_b, A_log,
        hpart, dtsums, nullptr, nullptr, nullptr, nullptr);
    k_scan_comb<<<64, 256, 0, stream>>>(hpart, dtsums, A_log, h_in);
    k_conv_scan<1><<<2 * NCHUNK, 512, 0, stream>>>(
        xm, conv_w, conv_b, xpwT, dtwT, dt_b, A_log,
        nullptr, nullptr, D_param, z_silu, h_in, y_buf);
    bgemm<3, 512><<<dim3(4, 64), 256, 0, stream>>>(
        y_buf, m_out_wT, m_out_b, gated, nullptr, gate_sig);
    k_out_ln<<<128, 256, 0, stream>>>(
        gated, out_wT, out_b, decL, ln_g, ln_bb, outp);
}

// Round 11
// 279.660 us; speedup vs baseline: 1.4983x; 1.0582x over previous
//
#include <hip/hip_runtime.h>
#include <hip/hip_bf16.h>

typedef __bf16 bf16x8_t __attribute__((ext_vector_type(8)));
typedef float f32x4_t __attribute__((ext_vector_type(4)));

__device__ __forceinline__ float sigmoidf_(float x) { return 1.0f / (1.0f + __expf(-x)); }
__device__ __forceinline__ float siluf_(float x) { return x * sigmoidf_(x); }
__device__ __forceinline__ float softplusf_(float x) {
    return fmaxf(x, 0.0f) + log1pf(__expf(-fabsf(x)));
}
__device__ __forceinline__ float b2f(ushort u) { return __uint_as_float(((unsigned)u) << 16); }
__device__ __forceinline__ ushort f2b(float f) {
    return (ushort)__bfloat16_as_ushort(__float2bfloat16(f));
}
// NOTE (journal): r9 global_load_lds staging -> 419us REGRESSION (kills compiler
// cross-barrier prefetch). r10 conv+scan recompute fusion -> 296us NEUTRAL-BAD
// (duplicated phases 1-3 > HBM saved; kernel is latency-bound not BW-bound).
// r11: r8 structure + CHUNK=16 (2 blocks/CU on scan kernels) + 32-row out_ln.

// ---------------------------------------------------------------------------
// k_prep: cast+transpose weights fp32 [K][N] -> bf16 [N][K]; transpose inputs.
// ---------------------------------------------------------------------------
__global__ __launch_bounds__(256) void k_prep(
    const float* __restrict__ dec_w, const float* __restrict__ enc_w,
    const float* __restrict__ in_w, const float* __restrict__ m_out_w,
    const float* __restrict__ out_w, const float* __restrict__ x_proj_w,
    const float* __restrict__ dt_w,
    const float* __restrict__ dec, const float* __restrict__ enc,
    __hip_bfloat16* __restrict__ dec_wT, __hip_bfloat16* __restrict__ enc_wT,
    __hip_bfloat16* __restrict__ in_wT, __hip_bfloat16* __restrict__ m_out_wT,
    __hip_bfloat16* __restrict__ out_wT, __hip_bfloat16* __restrict__ xpwT,
    __hip_bfloat16* __restrict__ dtwT,
    __hip_bfloat16* __restrict__ decL, __hip_bfloat16* __restrict__ encL)
{
    __shared__ float tile[64][65];
    if (blockIdx.x < 5312) {
        int gid = blockIdx.x * 256 + threadIdx.x;
        const float* src; __hip_bfloat16* dst; int lk, N, idx;
        if (gid < 262144)       { src = dec_w;    dst = dec_wT;   lk = 8; N = 1024; idx = gid; }
        else if (gid < 393216)  { src = enc_w;    dst = enc_wT;   lk = 8; N = 512;  idx = gid - 262144; }
        else if (gid < 917504)  { src = in_w;     dst = in_wT;    lk = 9; N = 1024; idx = gid - 393216; }
        else if (gid < 1179648) { src = m_out_w;  dst = m_out_wT; lk = 9; N = 512;  idx = gid - 917504; }
        else if (gid < 1310720) { src = out_w;    dst = out_wT;   lk = 9; N = 256;  idx = gid - 1179648; }
        else if (gid < 1343488) { src = x_proj_w; dst = xpwT;     lk = 9; N = 64;   idx = gid - 1310720; }
        else                    { src = dt_w;     dst = dtwT;     lk = 5; N = 512;  idx = gid - 1343488; }
        int K = 1 << lk;
        int n = idx >> lk, k = idx & (K - 1);
        dst[idx] = __float2bfloat16(src[(size_t)k * N + n]);
        return;
    }
    const int bid = blockIdx.x - 5312;
    const int t = threadIdx.x;
    const int ct = bid & 3;
    const int lt = (bid >> 2) & 63;
    const int sel = bid >> 8;
    const int b = sel & 1, ten = sel >> 1;
    const float* src = ten ? enc : dec;
    __hip_bfloat16* dst = ten ? encL : decL;
    const size_t ibase = (size_t)b * 256 * 4096 + (size_t)(ct * 64) * 4096 + (size_t)lt * 64;
#pragma unroll
    for (int i = 0; i < 16; ++i) {
        int c = i * 4 + (t >> 6), l = t & 63;
        tile[c][l] = src[ibase + (size_t)c * 4096 + l];
    }
    __syncthreads();
    const size_t obase = ((size_t)b * 4096 + (size_t)lt * 64) * 256 + ct * 64;
#pragma unroll
    for (int i = 0; i < 16; ++i) {
        int l = i * 4 + (t >> 6), c = t & 63;
        dst[obase + (size_t)l * 256 + c] = __float2bfloat16(tile[c][l]);
    }
}

// ---------------------------------------------------------------------------
// bf16 MFMA GEMM (128x128 tile, BK=32, 4 waves of 64x64). VGPR-staged.
// EPI 0: enc_p bf16 | EPI 1: combined bf16 + sigmoid(gate) bf16 (extra=enc_p)
// EPI 2: xm/silu(z) bf16 | EPI 3: v * extra (gate_sig bf16)
// ---------------------------------------------------------------------------
template <int EPI, int K>
__global__ __launch_bounds__(256) void bgemm(
    const __hip_bfloat16* __restrict__ A, const __hip_bfloat16* __restrict__ Bt,
    const float* __restrict__ bias, void* __restrict__ out0,
    void* __restrict__ out1, const void* __restrict__ extra)
{
    __shared__ ushort At[128 * 32];
    __shared__ ushort Bl[128 * 32];
    const int tid = threadIdx.x;
    const int wave = tid >> 6, lane = tid & 63;
    const int n0 = blockIdx.x * 128, m0 = blockIdx.y * 128;
    const int wm = (wave >> 1) * 64, wn = (wave & 1) * 64;
    f32x4_t acc[4][4] = {};
    const int fr = lane & 15, fq = (lane >> 4) * 8;

    for (int k0 = 0; k0 < K; k0 += 32) {
#pragma unroll
        for (int q = 0; q < 2; ++q) {
            int idx = q * 256 + tid;
            int row = idx >> 2, ch = (idx & 3) * 8;
            uint4 va = *(const uint4*)&A[(size_t)(m0 + row) * K + k0 + ch];
            uint4 vb = *(const uint4*)&Bt[(size_t)(n0 + row) * K + k0 + ch];
            *(uint4*)&At[row * 32 + ch] = va;
            *(uint4*)&Bl[row * 32 + ch] = vb;
        }
        __syncthreads();
        bf16x8_t af[4], bf[4];
#pragma unroll
        for (int i = 0; i < 4; ++i) {
            af[i] = *(bf16x8_t*)&At[(wm + i * 16 + fr) * 32 + fq];
            bf[i] = *(bf16x8_t*)&Bl[(wn + i * 16 + fr) * 32 + fq];
        }
#pragma unroll
        for (int i = 0; i < 4; ++i)
#pragma unroll
            for (int j = 0; j < 4; ++j)
                acc[i][j] = __builtin_amdgcn_mfma_f32_16x16x32_bf16(af[i], bf[j], acc[i][j], 0, 0, 0);
        __syncthreads();
    }

    const int col = lane & 15, rbase = (lane >> 4) * 4;
#pragma unroll
    for (int i = 0; i < 4; ++i) {
#pragma unroll
        for (int j = 0; j < 4; ++j) {
#pragma unroll
            for (int r = 0; r < 4; ++r) {
                int m = m0 + wm + i * 16 + rbase + r;
                int n = n0 + wn + j * 16 + col;
                float v = acc[i][j][r] + bias[n];
                if (EPI == 0) {
                    ((__hip_bfloat16*)out0)[(size_t)m * 512 + n] = __float2bfloat16(v);
                } else if (EPI == 1) {
                    if (n < 512) {
                        float ep = __bfloat162float(((const __hip_bfloat16*)extra)[(size_t)m * 512 + n]);
                        ((__hip_bfloat16*)out0)[(size_t)m * 512 + n] =
                            __float2bfloat16(fmaf(v, sigmoidf_(ep), ep));
                    } else {
                        ((__hip_bfloat16*)out1)[(size_t)m * 512 + (n - 512)] =
                            __float2bfloat16(sigmoidf_(v));
                    }
                } else if (EPI == 2) {
                    if (n < 512)
                        ((__hip_bfloat16*)out0)[(size_t)m * 512 + n] = __float2bfloat16(v);
                    else
                        ((__hip_bfloat16*)out1)[(size_t)m * 512 + (n - 512)] =
                            __float2bfloat16(siluf_(v));
                } else {
                    float g = __bfloat162float(((const __hip_bfloat16*)extra)[(size_t)m * 512 + n]);
                    ((__hip_bfloat16*)out0)[(size_t)m * 512 + n] = __float2bfloat16(v * g);
                }
            }
        }
    }
}

// ---------------------------------------------------------------------------
// k_conv_scan: conv + x_dbl + dt + chunk partial scan (r8 structure: stores
// u/dt/B/C once for k_scan_fin). CHUNK=16 -> 512 blocks = 2 blocks/CU.
// ---------------------------------------------------------------------------
#define CHUNK 16
#define NCHUNK 256

__global__ __launch_bounds__(512) void k_conv_scan(
    const __hip_bfloat16* __restrict__ xm, const float* __restrict__ conv_w,
    const float* __restrict__ conv_b, const __hip_bfloat16* __restrict__ xpwT,
    const __hip_bfloat16* __restrict__ dtwT, const float* __restrict__ dt_b,
    const float* __restrict__ A_log,
    __hip_bfloat16* __restrict__ u_out, float* __restrict__ Bm,
    float* __restrict__ Cm, __hip_bfloat16* __restrict__ dt_out,
    float* __restrict__ hpart, float* __restrict__ dtsums)
{
    __shared__ __align__(16) ushort us_dts[CHUNK][512 + 8];  // u, then dt (aliased)
    __shared__ __align__(16) ushort adt[CHUNK][32 + 8];
    __shared__ float BsL[CHUNK * 16];
    const int tid = threadIdx.x;
    const int wave = tid >> 6, lane = tid & 63;
    const int bl0 = blockIdx.x * CHUNK;
    const int l0 = bl0 & 4095;
    const int b = blockIdx.x >> 8;
    const int chunk = blockIdx.x & (NCHUNK - 1);
    const int fr = lane & 15, fq = (lane >> 4) * 8;
    const int col = lane & 15, rbase = (lane >> 4) * 4;

    // ---- phase 1: depthwise conv + silu; thread d keeps u[t] in registers
    float uarr[CHUNK];
    {
        const int d = tid;
        const float cw0 = conv_w[d * 4], cw1 = conv_w[d * 4 + 1];
        const float cw2 = conv_w[d * 4 + 2], cw3 = conv_w[d * 4 + 3];
        const float cb = conv_b[d];
        const ushort* xs = (const ushort*)xm;
        float x0 = (l0 >= 3) ? b2f(xs[(size_t)(bl0 - 3) * 512 + d]) : 0.f;
        float x1 = (l0 >= 2) ? b2f(xs[(size_t)(bl0 - 2) * 512 + d]) : 0.f;
        float x2 = (l0 >= 1) ? b2f(xs[(size_t)(bl0 - 1) * 512 + d]) : 0.f;
#pragma unroll
        for (int t = 0; t < CHUNK; ++t) {
            float x3 = b2f(xs[(size_t)(bl0 + t) * 512 + d]);
            float a = cb;
            a = fmaf(cw0, x0, a);
            a = fmaf(cw1, x1, a);
            a = fmaf(cw2, x2, a);
            a = fmaf(cw3, x3, a);
            float uv = siluf_(a);
            uarr[t] = uv;
            ushort ub = f2b(uv);
            us_dts[t][d] = ub;
            ((ushort*)u_out)[(size_t)(bl0 + t) * 512 + d] = ub;
            x0 = x1; x1 = x2; x2 = x3;
        }
    }
    __syncthreads();

    // ---- phase 2: x_dbl (M=16,N=64,K=512). waves 0..3: n-tile = wave
    if (wave < 4) {
        const int n0w = wave * 16;
        f32x4_t acc = {};
        const __hip_bfloat16* bp = xpwT + (size_t)(n0w + fr) * 512;
#pragma unroll
        for (int k0 = 0; k0 < 512; k0 += 32) {
            bf16x8_t af = *(bf16x8_t*)&us_dts[fr][k0 + fq];
            bf16x8_t bf = *(const bf16x8_t*)&bp[k0 + fq];
            acc = __builtin_amdgcn_mfma_f32_16x16x32_bf16(af, bf, acc, 0, 0, 0);
        }
#pragma unroll
        for (int r = 0; r < 4; ++r) {
            int m = rbase + r;
            int n = n0w + col;
            float v = acc[r];
            if (n < 32) {
                adt[m][n] = f2b(v);
            } else if (n < 48) {
                BsL[m * 16 + (n - 32)] = v;
                Bm[(size_t)(bl0 + m) * 16 + (n - 32)] = v;
            } else {
                Cm[(size_t)(bl0 + m) * 16 + (n - 48)] = v;
            }
        }
    }
    __syncthreads();   // us reads done -> dt may overwrite

    // ---- phase 3: dt (M=16,N=512,K=32). wave w: n-tiles w*4..w*4+3
    {
        bf16x8_t af = *(bf16x8_t*)&adt[fr][fq];
#pragma unroll
        for (int t = 0; t < 4; ++t) {
            int nt = wave * 4 + t;
            bf16x8_t bf = *(const bf16x8_t*)&dtwT[(size_t)(nt * 16 + fr) * 32 + fq];
            f32x4_t acc = {};
            acc = __builtin_amdgcn_mfma_f32_16x16x32_bf16(af, bf, acc, 0, 0, 0);
#pragma unroll
            for (int r = 0; r < 4; ++r) {
                int m = rbase + r;
                int n = nt * 16 + col;
                ushort dv = f2b(softplusf_(acc[r] + dt_b[n]));
                us_dts[m][n] = dv;
                ((ushort*)dt_out)[(size_t)(bl0 + m) * 512 + n] = dv;
            }
        }
    }
    __syncthreads();

    // ---- phase 4: chunk partial scan (thread d; u in regs, dt/B in LDS)
    {
        const int d = tid;
        float Av[16];
#pragma unroll
        for (int n = 0; n < 16; n += 4) {
            float4 al = *(const float4*)&A_log[d * 16 + n];
            Av[n + 0] = -__expf(al.x);
            Av[n + 1] = -__expf(al.y);
            Av[n + 2] = -__expf(al.z);
            Av[n + 3] = -__expf(al.w);
        }
        float h[16] = {};
        float dtsum = 0.f;
#pragma unroll
        for (int t = 0; t < CHUNK; ++t) {
            float dtv = b2f(us_dts[t][d]);
            float dtu = dtv * uarr[t];
            dtsum += dtv;
            const float* Bt = &BsL[t * 16];
#pragma unroll
            for (int n = 0; n < 16; ++n)
                h[n] = fmaf(h[n], __expf(dtv * Av[n]), dtu * Bt[n]);
        }
        const size_t sidx = ((size_t)b * NCHUNK + chunk) * 512 + d;
        const size_t idx = sidx * 16;
#pragma unroll
        for (int n = 0; n < 16; n += 4)
            *(float4*)&hpart[idx + n] = make_float4(h[n], h[n + 1], h[n + 2], h[n + 3]);
        dtsums[sidx] = dtsum;
    }
}

__global__ __launch_bounds__(256) void k_scan_comb(
    const float* __restrict__ hpart, const float* __restrict__ dtsums,
    const float* __restrict__ A_log, float* __restrict__ h_in)
{
    const int gid = blockIdx.x * 256 + threadIdx.x;
    const int n = gid & 15;
    const int d = (gid >> 4) & 511;
    const int b = gid >> 13;
    const float Av = -__expf(A_log[d * 16 + n]);
    float h = 0.f;
    for (int c = 0; c < NCHUNK; ++c) {
        const size_t sidx = ((size_t)b * NCHUNK + c) * 512 + d;
        const size_t idx = sidx * 16 + n;
        h_in[idx] = h;
        h = fmaf(h, __expf(Av * dtsums[sidx]), hpart[idx]);
    }
}

__global__ __launch_bounds__(512) void k_scan_fin(
    const __hip_bfloat16* __restrict__ dt, const __hip_bfloat16* __restrict__ u,
    const float* __restrict__ Bmp, const float* __restrict__ Cmp,
    const float* __restrict__ A_log, const float* __restrict__ Dp,
    const __hip_bfloat16* __restrict__ zs, const float* __restrict__ h_in,
    __hip_bfloat16* __restrict__ yout)
{
    __shared__ float Bs[CHUNK * 16];
    __shared__ float Cs[CHUNK * 16];
    const int d = threadIdx.x;
    const int chunk = blockIdx.x & (NCHUNK - 1);
    const int b = blockIdx.x >> 8;
    const size_t row0 = (size_t)b * 4096 + (size_t)chunk * CHUNK;

    if (d < CHUNK * 16) {
        Bs[d] = Bmp[row0 * 16 + d];
        Cs[d] = Cmp[row0 * 16 + d];
    }
    float Av[16];
#pragma unroll
    for (int n = 0; n < 16; n += 4) {
        float4 al = *(const float4*)&A_log[d * 16 + n];
        Av[n + 0] = -__expf(al.x);
        Av[n + 1] = -__expf(al.y);
        Av[n + 2] = -__expf(al.z);
        Av[n + 3] = -__expf(al.w);
    }
    const float Dv = Dp[d];
    float h[16];
    const size_t idx = (((size_t)b * NCHUNK + chunk) * 512 + d) * 16;
#pragma unroll
    for (int n = 0; n < 16; n += 4) {
        float4 hv = *(const float4*)&h_in[idx + n];
        h[n] = hv.x; h[n + 1] = hv.y; h[n + 2] = hv.z; h[n + 3] = hv.w;
    }
    __syncthreads();

    const ushort* dtp = (const ushort*)dt + row0 * 512 + d;
    const ushort* up = (const ushort*)u + row0 * 512 + d;
    const ushort* zp = (const ushort*)zs + row0 * 512 + d;
    __hip_bfloat16* yp = yout + row0 * 512 + d;
#pragma unroll
    for (int t = 0; t < CHUNK; ++t) {
        float dtv = b2f(dtp[(size_t)t * 512]);
        float uv = b2f(up[(size_t)t * 512]);
        float zv = b2f(zp[(size_t)t * 512]);
        float dtu = dtv * uv;
        const float* Bt = &Bs[t * 16];
        const float* Ct = &Cs[t * 16];
        float y = 0.f;
#pragma unroll
        for (int n = 0; n < 16; ++n) {
            h[n] = fmaf(h[n], __expf(dtv * Av[n]), dtu * Bt[n]);
            y = fmaf(h[n], Ct[n], y);
        }
        yp[(size_t)t * 512] = __float2bfloat16((y + uv * Dv) * zv);
    }
}

// ---------------------------------------------------------------------------
// k_out_ln: final GEMM (M-tile 32, N=256, K=512) + out_b + residual +
// LayerNorm over C=256 + transposed write. 256 blocks x 256 threads
// (was 128 blocks = half the CUs idle).
// ---------------------------------------------------------------------------
__global__ __launch_bounds__(256) void k_out_ln(
    const __hip_bfloat16* __restrict__ A, const __hip_bfloat16* __restrict__ Bt,
    const float* __restrict__ bias, const __hip_bfloat16* __restrict__ decL,
    const float* __restrict__ ln_g, const float* __restrict__ ln_b,
    float* __restrict__ outp)
{
    __shared__ ushort At[32 * 32];
    __shared__ ushort Bl[256 * 32];
    __shared__ float red[4][32][2];
    __shared__ float lmu[32], lsc[32];
    const int tid = threadIdx.x;
    const int wave = tid >> 6, lane = tid & 63;
    const int m0 = blockIdx.x * 32;
    const int wn = wave * 64;
    f32x4_t acc[2][4] = {};
    const int fr = lane & 15, fq = (lane >> 4) * 8;

    for (int k0 = 0; k0 < 512; k0 += 32) {
        if (tid < 128) {
            int row = tid >> 2, ch = (tid & 3) * 8;
            *(uint4*)&At[row * 32 + ch] = *(const uint4*)&A[(size_t)(m0 + row) * 512 + k0 + ch];
        }
#pragma unroll
        for (int q = 0; q < 4; ++q) {
            int idx = q * 256 + tid;
            int row = idx >> 2, ch = (idx & 3) * 8;
            *(uint4*)&Bl[row * 32 + ch] = *(const uint4*)&Bt[(size_t)row * 512 + k0 + ch];
        }
        __syncthreads();
        bf16x8_t af[2], bf[4];
#pragma unroll
        for (int i = 0; i < 2; ++i)
            af[i] = *(bf16x8_t*)&At[(i * 16 + fr) * 32 + fq];
#pragma unroll
        for (int j = 0; j < 4; ++j)
            bf[j] = *(bf16x8_t*)&Bl[(wn + j * 16 + fr) * 32 + fq];
#pragma unroll
        for (int i = 0; i < 2; ++i)
#pragma unroll
            for (int j = 0; j < 4; ++j)
                acc[i][j] = __builtin_amdgcn_mfma_f32_16x16x32_bf16(af[i], bf[j], acc[i][j], 0, 0, 0);
        __syncthreads();
    }

    const int col = lane & 15, rbase = (lane >> 4) * 4;
#pragma unroll
    for (int i = 0; i < 2; ++i) {
#pragma unroll
        for (int r = 0; r < 4; ++r) {
            int ml = i * 16 + rbase + r;
            int m = m0 + ml;
            float s = 0.f, sq = 0.f;
#pragma unroll
            for (int j = 0; j < 4; ++j) {
                int n = wn + j * 16 + col;
                float dv = b2f(((const ushort*)decL)[(size_t)m * 256 + n]);
                float v = acc[i][j][r] + bias[n] + dv;
                acc[i][j][r] = v;
                s += v;
                sq = fmaf(v, v, sq);
            }
            s += __shfl_xor(s, 1);  sq += __shfl_xor(sq, 1);
            s += __shfl_xor(s, 2);  sq += __shfl_xor(sq, 2);
            s += __shfl_xor(s, 4);  sq += __shfl_xor(sq, 4);
            s += __shfl_xor(s, 8);  sq += __shfl_xor(sq, 8);
            if (col == 0) { red[wave][ml][0] = s; red[wave][ml][1] = sq; }
        }
    }
    __syncthreads();
    if (tid < 32) {
        float s  = red[0][tid][0] + red[1][tid][0] + red[2][tid][0] + red[3][tid][0];
        float sq = red[0][tid][1] + red[1][tid][1] + red[2][tid][1] + red[3][tid][1];
        float mu = s * (1.0f / 256.0f);
        float var = sq * (1.0f / 256.0f) - mu * mu;
        lmu[tid] = mu;
        lsc[tid] = rsqrtf(var + 1e-5f);
    }
    __syncthreads();
    const int bb = m0 >> 12;
    const int lpos0 = m0 & 4095;
#pragma unroll
    for (int i = 0; i < 2; ++i) {
#pragma unroll
        for (int r = 0; r < 4; ++r) {
            int ml = i * 16 + rbase + r;
            float mu = lmu[ml], sc = lsc[ml];
#pragma unroll
            for (int j = 0; j < 4; ++j) {
                int n = wn + j * 16 + col;
                float v = (acc[i][j][r] - mu) * sc * ln_g[n] + ln_b[n];
                outp[(size_t)bb * (256 * 4096) + (size_t)n * 4096 + lpos0 + ml] = v;
            }
        }
    }
}

// ---------------------------------------------------------------------------
extern "C" void kernel_launch(void* const* d_in, const int* in_sizes, int n_in,
                              void* d_out, int out_size, void* d_ws, size_t ws_size,
                              hipStream_t stream)
{
    const float* decoder_feat = (const float*)d_in[0];
    const float* encoder_feat = (const float*)d_in[1];
    const float* dec_w = (const float*)d_in[2];
    const float* dec_b = (const float*)d_in[3];
    const float* enc_w = (const float*)d_in[4];
    const float* enc_b = (const float*)d_in[5];
    const float* out_w = (const float*)d_in[6];
    const float* out_b = (const float*)d_in[7];
    const float* ln_g = (const float*)d_in[8];
    const float* ln_bb = (const float*)d_in[9];
    const float* in_w = (const float*)d_in[10];
    const float* in_b = (const float*)d_in[11];
    const float* conv_w = (const float*)d_in[12];
    const float* conv_b = (const float*)d_in[13];
    const float* x_proj_w = (const float*)d_in[14];
    const float* dt_w = (const float*)d_in[15];
    const float* dt_b = (const float*)d_in[16];
    const float* A_log = (const float*)d_in[17];
    const float* D_param = (const float*)d_in[18];
    const float* m_out_w = (const float*)d_in[19];
    const float* m_out_b = (const float*)d_in[20];

    float* outp = (float*)d_out;
    char* ws = (char*)d_ws;
    const size_t MB = 1024ull * 1024;
    __hip_bfloat16* decL     = (__hip_bfloat16*)(ws + 0 * MB);    // 4 MB
    __hip_bfloat16* encL     = (__hip_bfloat16*)(ws + 4 * MB);    // 4 MB
    __hip_bfloat16* dec_wT   = (__hip_bfloat16*)(ws + 8 * MB);
    __hip_bfloat16* enc_wT   = (__hip_bfloat16*)(ws + 9 * MB);
    __hip_bfloat16* in_wT    = (__hip_bfloat16*)(ws + 10 * MB);
    __hip_bfloat16* m_out_wT = (__hip_bfloat16*)(ws + 11 * MB);
    __hip_bfloat16* out_wT   = (__hip_bfloat16*)(ws + 12 * MB);
    __hip_bfloat16* xpwT     = (__hip_bfloat16*)(ws + 12 * MB + 262144);
    __hip_bfloat16* dtwT     = (__hip_bfloat16*)(ws + 12 * MB + 262144 + 65536);
    __hip_bfloat16* enc_pb   = (__hip_bfloat16*)(ws + 13 * MB);   // 8 MB of 13..29 slot
    __hip_bfloat16* combined = (__hip_bfloat16*)(ws + 29 * MB);   // 8 MB; reused: y
    __hip_bfloat16* gate_sig = (__hip_bfloat16*)(ws + 37 * MB);   // 8 MB
    __hip_bfloat16* xm       = (__hip_bfloat16*)(ws + 45 * MB);   // 8 MB; reused: gated
    __hip_bfloat16* z_silu   = (__hip_bfloat16*)(ws + 53 * MB);   // 8 MB
    __hip_bfloat16* u_buf    = (__hip_bfloat16*)(ws + 61 * MB);   // 8 MB
    __hip_bfloat16* dt_buf   = (__hip_bfloat16*)(ws + 69 * MB);   // 8 MB (bf16)
    float* h_in              = (float*)(ws + 77 * MB);            // 16 MB (77..93)
    float* Bm                = (float*)(ws + 93 * MB);            // 0.5 MB
    float* Cm                = (float*)(ws + 93 * MB + 524288);   // 0.5 MB
    float* dtsums            = (float*)(ws + 94 * MB);            // 1 MB
    // scan scratch (dead-slot reuse; stream-ordered, safe)
    float* hpart = (float*)(ws + 13 * MB);       // 16 MB; enc_pb dead after bgemm<1>
    __hip_bfloat16* y_buf = combined;            // combined dead after bgemm<2>
    __hip_bfloat16* gated = xm;                  // xm dead after k_conv_scan

    k_prep<<<6336, 256, 0, stream>>>(
        dec_w, enc_w, in_w, m_out_w, out_w, x_proj_w, dt_w,
        decoder_feat, encoder_feat,
        dec_wT, enc_wT, in_wT, m_out_wT, out_wT, xpwT, dtwT, decL, encL);
    bgemm<0, 256><<<dim3(4, 64), 256, 0, stream>>>(
        encL, enc_wT, enc_b, enc_pb, nullptr, nullptr);
    bgemm<1, 256><<<dim3(8, 64), 256, 0, stream>>>(
        decL, dec_wT, dec_b, combined, gate_sig, enc_pb);
    bgemm<2, 512><<<dim3(8, 64), 256, 0, stream>>>(
        combined, in_wT, in_b, xm, z_silu, nullptr);
    k_conv_scan<<<2 * NCHUNK, 512, 0, stream>>>(
        xm, conv_w, conv_b, xpwT, dtwT, dt_b, A_log,
        u_buf, Bm, Cm, dt_buf, hpart, dtsums);
    k_scan_comb<<<64, 256, 0, stream>>>(hpart, dtsums, A_log, h_in);
    k_scan_fin<<<2 * NCHUNK, 512, 0, stream>>>(
        dt_buf, u_buf, Bm, Cm, A_log, D_param, z_silu, h_in, y_buf);
    bgemm<3, 512><<<dim3(4, 64), 256, 0, stream>>>(
        y_buf, m_out_wT, m_out_b, gated, nullptr, gate_sig);
    k_out_ln<<<256, 256, 0, stream>>>(
        gated, out_wT, out_b, decL, ln_g, ln_bb, outp);
}